// Round 1
// baseline (132.774 us; speedup 1.0000x reference)
//
#include <hip/hip_runtime.h>
#include <math.h>

// y[b,f,t] = | x[t] - C_f*w_f * S[t] |,  S[t] = sum_{j=0}^{497} a^j x[t-1-j] (edge-padded)
// S[t+1] = a*S[t] + x[t] - a^498 * x[t-498]  -> wave-parallel weighted scan, 256 samples/round.

constexpr int T    = 8000;
constexpr int F    = 64;
constexpr int B    = 32;
constexpr int KM1  = 498;               // K-1 (lag)
constexpr int ROUND = 256;              // samples per wave-round (4 per lane)
constexpr int NROUND = (T + ROUND - 1) / ROUND;  // 32

__global__ __launch_bounds__(256) void willmore_scan_kernel(
    const float* __restrict__ x, const float* __restrict__ a,
    const float* __restrict__ w, float* __restrict__ out)
{
    const int wid  = (blockIdx.x * blockDim.x + threadIdx.x) >> 6;  // row = b*F + f
    const int lane = threadIdx.x & 63;
    if (wid >= B * F) return;
    const int f = wid % F;

    const float* xr   = x   + (size_t)wid * T;
    float*       orow = out + (size_t)wid * T;

    // --- per-row constants (double, once) ---
    const double ad = (double)a[f];
    double p = ad, a498d = 1.0;
    for (int e = KM1; e; e >>= 1) { if (e & 1) a498d *= p; p *= p; }
    const double sumgeo = (1.0 - a498d) / (1.0 - ad);   // sum_{j=0}^{497} a^j
    const float  af     = (float)ad;
    const float  na498  = (float)(-a498d);
    const float  g      = (float)(1.0 / sumgeo) * w[f]; // C * w
    const double a4d    = ad * ad * ad * ad;
    const float  alane  = (float)exp2(log2(a4d) * (double)lane);  // a^(4*lane)
    float wstep[6];
    double tpow = a4d;
    #pragma unroll
    for (int s = 0; s < 6; ++s) { wstep[s] = (float)tpow; tpow *= tpow; }
    const float a256 = (float)tpow;                      // a^256

    // --- running state: S = S[tR] (state entering current round) ---
    float S = xr[0] * (float)sumgeo;                     // S[0]

    int tR = 0;
    for (int rnd = 0; rnd < NROUND; ++rnd, tR += ROUND) {
        const int tbase = tR + 4 * lane;
        const bool tail = (tR + ROUND > T);

        float4 xv;
        if (!tail) {
            xv = *(const float4*)(xr + tbase);
        } else {
            xv.x = xr[min(tbase,     T - 1)];
            xv.y = xr[min(tbase + 1, T - 1)];
            xv.z = xr[min(tbase + 2, T - 1)];
            xv.w = xr[min(tbase + 3, T - 1)];
        }

        const int lag = tbase - KM1;
        float l0, l1, l2, l3;
        if (lag >= 0 && !tail) {
            const float2* lp = (const float2*)(xr + lag);  // lag is even -> 8B aligned
            float2 la = lp[0], lb = lp[1];
            l0 = la.x; l1 = la.y; l2 = lb.x; l3 = lb.y;
        } else {
            l0 = xr[max(min(lag,     T - 1), 0)];
            l1 = xr[max(min(lag + 1, T - 1), 0)];
            l2 = xr[max(min(lag + 2, T - 1), 0)];
            l3 = xr[max(min(lag + 3, T - 1), 0)];
        }

        const float u0 = fmaf(na498, l0, xv.x);
        const float u1 = fmaf(na498, l1, xv.y);
        const float u2 = fmaf(na498, l2, xv.z);
        const float u3 = fmaf(na498, l3, xv.w);

        // local inclusive weighted scan (4 elems)
        const float q0 = u0;
        const float q1 = fmaf(af, q0, u1);
        const float q2 = fmaf(af, q1, u2);
        const float q3 = fmaf(af, q2, u3);

        // wave inclusive scan of lane aggregates, ratio a^4
        float G = q3;
        #pragma unroll
        for (int s = 0; s < 6; ++s) {
            const float gup = __shfl_up(G, 1 << s, 64);
            const float ws  = (lane >= (1 << s)) ? wstep[s] : 0.0f;
            G = fmaf(ws, gup, G);
        }
        float Gprev = __shfl_up(G, 1, 64);
        if (lane == 0) Gprev = 0.0f;

        // state entering this lane's 4 elements: S[tR + 4*lane]
        float s0 = fmaf(alane, S, Gprev);
        const float y0 = fabsf(fmaf(-g, s0, xv.x));
        const float s1 = fmaf(af, s0, u0);
        const float y1 = fabsf(fmaf(-g, s1, xv.y));
        const float s2 = fmaf(af, s1, u1);
        const float y2 = fabsf(fmaf(-g, s2, xv.z));
        const float s3 = fmaf(af, s2, u2);
        const float y3 = fabsf(fmaf(-g, s3, xv.w));

        // carry to next round: S[tR+256] = a^256 * S + G[63]
        const float Slast = __shfl(G, 63, 64);
        S = fmaf(a256, S, Slast);

        if (!tail || (tbase + 3 < T)) {
            *(float4*)(orow + tbase) = make_float4(y0, y1, y2, y3);
        }
        // (T % 4 == 0 and ROUND % 4 == 0, so no partial-vector stores occur)
    }
}

extern "C" void kernel_launch(void* const* d_in, const int* in_sizes, int n_in,
                              void* d_out, int out_size, void* d_ws, size_t ws_size,
                              hipStream_t stream) {
    const float* x = (const float*)d_in[0];
    const float* a = (const float*)d_in[1];
    const float* w = (const float*)d_in[2];
    float* out = (float*)d_out;

    const int rows = B * F;                 // 2048 waves, one per row
    const int threads = 256;                // 4 waves/block
    const int blocks = rows * 64 / threads; // 512
    hipLaunchKernelGGL(willmore_scan_kernel, dim3(blocks), dim3(threads), 0, stream,
                       x, a, w, out);
}

// Round 2
// 122.516 us; speedup vs baseline: 1.0837x; 1.0837x over previous
//
#include <hip/hip_runtime.h>
#include <math.h>

// y[b,f,t] = | x[t] - C_f*w_f * S[t] |,  S[t] = sum_{j=0}^{497} a^j x[t-1-j] (edge-padded)
// S[t+1] = a*S[t] + x[t] - a^498 * x[t-498]
//
// R1: S has a finite 498-sample window -> row segments are independent given a
// redundant warm-up reduction. 4 segments/row x 2048 rows = 8192 waves (100% occ cap)
// vs R0's 2048 (latency-bound, VALUBusy 9.5%). Block = row, wave-in-block = segment
// so warm-up re-reads hit the local L1/L2.

constexpr int T     = 8000;
constexpr int F     = 64;
constexpr int B     = 32;
constexpr int KM1   = 498;                 // K-1 (lag)
constexpr int NSEG  = 4;
constexpr int SEGLEN = T / NSEG;           // 2000
constexpr int ROUND = 256;                 // samples per wave-round (4 per lane)
constexpr int NFULL = SEGLEN / ROUND;      // 7 full rounds
constexpr int TAILN = SEGLEN - NFULL * ROUND;  // 208 (=4*52, float4-aligned)

__global__ __launch_bounds__(256) void willmore_scan_kernel(
    const float* __restrict__ x, const float* __restrict__ a,
    const float* __restrict__ w, float* __restrict__ out)
{
    const int row  = blockIdx.x;                // b*F + f
    const int seg  = threadIdx.x >> 6;          // 0..3
    const int lane = threadIdx.x & 63;
    const int f = row % F;

    const float* xr   = x   + (size_t)row * T;
    float*       orow = out + (size_t)row * T;

    // --- per-row constants ---
    const double ad = (double)a[f];
    double p = ad, a498d = 1.0;
    for (int e = KM1; e; e >>= 1) { if (e & 1) a498d *= p; p *= p; }
    const double sumgeo = (1.0 - a498d) / (1.0 - ad);   // sum_{j=0}^{497} a^j
    const float  af     = (float)ad;
    const float  na498  = (float)(-a498d);
    const float  g      = (float)(1.0 / sumgeo) * w[f]; // C * w
    const double a4d    = ad * ad * ad * ad;
    const float  alane  = (float)exp2(log2(a4d) * (double)lane);  // a^(4*lane)
    float wstep[6];
    double tpow = a4d;
    #pragma unroll
    for (int s = 0; s < 6; ++s) { wstep[s] = (float)tpow; tpow *= tpow; }
    const float a256 = (float)tpow;                      // a^256

    const int t0 = seg * SEGLEN;

    // --- warm-up: S[t0] = sum_{j=0}^{497} a^j x[t0-1-j], edge-clamped ---
    // lane l covers idx = t0-512+8l+i (i=0..7), j = 511-8l-i; weight 0 if j>=498.
    float S;
    {
        const int base = t0 - 512 + 8 * lane;
        float xs[8];
        if (t0 == 0) {
            #pragma unroll
            for (int i = 0; i < 8; ++i) xs[i] = xr[max(base + i, 0)];
        } else {
            const float4 v0 = *(const float4*)(xr + base);
            const float4 v1 = *(const float4*)(xr + base + 4);
            xs[0]=v0.x; xs[1]=v0.y; xs[2]=v0.z; xs[3]=v0.w;
            xs[4]=v1.x; xs[5]=v1.y; xs[6]=v1.z; xs[7]=v1.w;
        }
        #pragma unroll
        for (int i = 0; i < 8; ++i) { if (511 - 8*lane - i >= KM1) xs[i] = 0.0f; }
        // h = sum_i xs[i] * a^(7-i)
        float h = xs[0];
        #pragma unroll
        for (int i = 1; i < 8; ++i) h = fmaf(h, af, xs[i]);
        // lane weight a^(504-8*lane), repeated squaring (9 bits)
        const int e = 504 - 8 * lane;
        float wl = 1.0f, pb = af;
        #pragma unroll
        for (int s = 0; s < 9; ++s) { if (e & (1 << s)) wl *= pb; pb *= pb; }
        float contrib = wl * h;
        #pragma unroll
        for (int s = 1; s < 64; s <<= 1) contrib += __shfl_xor(contrib, s, 64);
        S = contrib;
    }

    // --- scan over this segment: 7 full rounds + 208-sample tail ---
    int tR = t0;
    for (int rnd = 0; rnd <= NFULL; ++rnd, tR += ROUND) {
        const bool tail = (rnd == NFULL);
        const int tbase = tR + 4 * lane;

        float4 xv;
        if (!tail) {
            xv = *(const float4*)(xr + tbase);
        } else {
            xv.x = xr[min(tbase,     T - 1)];
            xv.y = xr[min(tbase + 1, T - 1)];
            xv.z = xr[min(tbase + 2, T - 1)];
            xv.w = xr[min(tbase + 3, T - 1)];
        }

        const int lag = tbase - KM1;
        float l0, l1, l2, l3;
        if (lag >= 0 && !tail) {
            const float2* lp = (const float2*)(xr + lag);  // lag even -> 8B aligned
            const float2 la = lp[0], lb = lp[1];
            l0 = la.x; l1 = la.y; l2 = lb.x; l3 = lb.y;
        } else {
            l0 = xr[max(min(lag,     T - 1), 0)];
            l1 = xr[max(min(lag + 1, T - 1), 0)];
            l2 = xr[max(min(lag + 2, T - 1), 0)];
            l3 = xr[max(min(lag + 3, T - 1), 0)];
        }

        const float u0 = fmaf(na498, l0, xv.x);
        const float u1 = fmaf(na498, l1, xv.y);
        const float u2 = fmaf(na498, l2, xv.z);
        const float u3 = fmaf(na498, l3, xv.w);

        // local inclusive weighted scan (4 elems)
        const float q1 = fmaf(af, u0, u1);
        const float q2 = fmaf(af, q1, u2);
        const float q3 = fmaf(af, q2, u3);

        // wave inclusive scan of lane aggregates, ratio a^4
        float G = q3;
        #pragma unroll
        for (int s = 0; s < 6; ++s) {
            const float gup = __shfl_up(G, 1 << s, 64);
            const float ws  = (lane >= (1 << s)) ? wstep[s] : 0.0f;
            G = fmaf(ws, gup, G);
        }
        float Gprev = __shfl_up(G, 1, 64);
        if (lane == 0) Gprev = 0.0f;

        // state entering this lane's 4 elements: S[tR + 4*lane]
        const float s0 = fmaf(alane, S, Gprev);
        const float y0 = fabsf(fmaf(-g, s0, xv.x));
        const float s1 = fmaf(af, s0, u0);
        const float y1 = fabsf(fmaf(-g, s1, xv.y));
        const float s2 = fmaf(af, s1, u1);
        const float y2 = fabsf(fmaf(-g, s2, xv.z));
        const float s3 = fmaf(af, s2, u2);
        const float y3 = fabsf(fmaf(-g, s3, xv.w));

        if (!tail) {
            *(float4*)(orow + tbase) = make_float4(y0, y1, y2, y3);
            // carry to next round: S[tR+256] = a^256 * S + G[63]
            const float Slast = __shfl(G, 63, 64);
            S = fmaf(a256, S, Slast);
        } else if (4 * lane < TAILN) {
            *(float4*)(orow + tbase) = make_float4(y0, y1, y2, y3);
        }
    }
}

extern "C" void kernel_launch(void* const* d_in, const int* in_sizes, int n_in,
                              void* d_out, int out_size, void* d_ws, size_t ws_size,
                              hipStream_t stream) {
    const float* x = (const float*)d_in[0];
    const float* a = (const float*)d_in[1];
    const float* w = (const float*)d_in[2];
    float* out = (float*)d_out;

    const int blocks = B * F;   // one block per row; 4 waves = 4 segments
    hipLaunchKernelGGL(willmore_scan_kernel, dim3(blocks), dim3(256), 0, stream,
                       x, a, w, out);
}